// Round 1
// baseline (2080.564 us; speedup 1.0000x reference)
//
#include <hip/hip_runtime.h>

namespace {
constexpr int Tn = 4096;
constexpr int Kn = 64;
constexpr int BATCH = 128;
constexpr int START_TAG = 62;
constexpr int STOP_TAG = 63;
constexpr float NEGV = -10000.0f;
constexpr int CH = 64;            // backtrace chunk length
constexpr int NCH = Tn / CH;      // 64 chunks
constexpr int GL = 8;             // feats burst length
constexpr int NG = Tn / GL;       // 512 groups
constexpr int RS = 32;            // delta/max LDS ring (steps), pow2
constexpr int RB = 128;           // backpointer LDS ring (steps), pow2

__device__ __forceinline__ float rfl(float x) {
    return __uint_as_float(__builtin_amdgcn_readfirstlane(__float_as_uint(x)));
}
__device__ __forceinline__ void cfence() { __asm__ volatile("" ::: "memory"); }
__device__ __forceinline__ void lgkm0() { __asm__ volatile("s_waitcnt lgkmcnt(0)" ::: "memory"); }
__device__ __forceinline__ int imin(int a, int b) { return a < b ? a : b; }

__global__ __launch_bounds__(256, 1)
void crf_kernel(const float* __restrict__ feats,   // [B,T,K]
                const int* __restrict__ tags,      // [B,T]
                const float* __restrict__ trans,   // [K,K] trans[next,prev]
                float* __restrict__ out,           // [B] nll | [B] path_score | [B,T] path
                unsigned char* __restrict__ bp8)   // [B,T,K] backpointers
{
    const int tid = threadIdx.x;
    const int lane = tid & 63;
    const int wid = tid >> 6;
    const int b = blockIdx.x & (BATCH - 1);
    const size_t fb = (size_t)b * Tn * Kn;

    __shared__ float gw[4];
    __shared__ __align__(16) float vbuf[Kn];            // fwd broadcast buffer
    __shared__ __align__(16) float ring_v[RS][Kn];      // vit: delta_t vectors
    __shared__ float ring_m[RS][Kn];                    // vit: pre-feat max m_t
    __shared__ unsigned char ring_bp[RB][Kn];           // vit: backpointers
    __shared__ unsigned char snap[NCH * Kn];
    __shared__ unsigned char echain[NCH];
    __shared__ int prog_a[Kn], prog_b[Kn], prog_c[Kn], prog_d[Kn];
    __shared__ int done_b[Kn], done_c[Kn];

    if (blockIdx.x < BATCH) {
        // ================= forward log-partition + gold -> nll =================
        // ---- gold: exactly the proven 256-thread reduction ----
        float gold = 0.0f;
        {
            const int t0 = tid * (Tn / 256);
            int prev = (tid == 0) ? START_TAG : tags[(size_t)b * Tn + t0 - 1];
            for (int k = 0; k < Tn / 256; ++k) {
                const int t = t0 + k;
                const int tg = tags[(size_t)b * Tn + t];
                gold += trans[tg * Kn + prev] + feats[fb + (size_t)t * Kn + tg];
                prev = tg;
            }
            if (tid == 255) gold += trans[STOP_TAG * Kn + prev];
            #pragma unroll
            for (int off = 32; off; off >>= 1) gold += __shfl_down(gold, off);
            if (lane == 0) gw[wid] = gold;
        }
        __syncthreads();
        if (wid != 0) return;   // single wave owns the whole recurrence

        // lane j holds the FULL row exp(trans[j, 0..63]) in registers
        float ES[Kn];
        #pragma unroll
        for (int q = 0; q < Kn / 4; ++q) {
            const float4 t4 = ((const float4*)(trans + lane * Kn))[q];
            ES[4*q+0] = __expf(t4.x); ES[4*q+1] = __expf(t4.y);
            ES[4*q+2] = __expf(t4.z); ES[4*q+3] = __expf(t4.w);
        }
        float v = (lane == START_TAG) ? 1.0f : 0.0f;  // exp-domain one-hot
        float O = 0.0f;
        float fc[GL], fn[GL], Fc[GL];
        #pragma unroll
        for (int k = 0; k < GL; ++k) fc[k] = feats[fb + (size_t)k * Kn + lane];
        for (int g = 0; g < NG; ++g) {
            if (g + 1 < NG) {
                const size_t base = fb + (size_t)(g + 1) * GL * Kn + lane;
                #pragma unroll
                for (int k = 0; k < GL; ++k) fn[k] = feats[base + (size_t)k * Kn];
            }
            #pragma unroll
            for (int k = 0; k < GL; ++k) Fc[k] = __expf(fc[k]);
            #pragma unroll
            for (int k = 0; k < GL; ++k) {
                // ONE LDS round trip, no barrier: own write -> broadcast reads
                vbuf[lane] = v;
                lgkm0();
                const float4* vp = (const float4*)vbuf;
                float wq[4];
                #pragma unroll
                for (int q = 0; q < 4; ++q) {
                    const float4 v0 = vp[4*q+0], v1 = vp[4*q+1],
                                 v2 = vp[4*q+2], v3 = vp[4*q+3];
                    float s0 = 0.f, s1 = 0.f, s2 = 0.f, s3 = 0.f;
                    s0 = fmaf(ES[16*q+0],  v0.x, s0); s1 = fmaf(ES[16*q+1],  v0.y, s1);
                    s2 = fmaf(ES[16*q+2],  v0.z, s2); s3 = fmaf(ES[16*q+3],  v0.w, s3);
                    s0 = fmaf(ES[16*q+4],  v1.x, s0); s1 = fmaf(ES[16*q+5],  v1.y, s1);
                    s2 = fmaf(ES[16*q+6],  v1.z, s2); s3 = fmaf(ES[16*q+7],  v1.w, s3);
                    s0 = fmaf(ES[16*q+8],  v2.x, s0); s1 = fmaf(ES[16*q+9],  v2.y, s1);
                    s2 = fmaf(ES[16*q+10], v2.z, s2); s3 = fmaf(ES[16*q+11], v2.w, s3);
                    s0 = fmaf(ES[16*q+12], v3.x, s0); s1 = fmaf(ES[16*q+13], v3.y, s1);
                    s2 = fmaf(ES[16*q+14], v3.z, s2); s3 = fmaf(ES[16*q+15], v3.w, s3);
                    wq[q] = (s0 + s1) + (s2 + s3);
                }
                const float w = ((wq[0] + wq[1]) + (wq[2] + wq[3])) * Fc[k];
                const float wz = rfl(w);
                O += __logf(wz);
                v = w * __builtin_amdgcn_rcpf(wz);
            }
            #pragma unroll
            for (int k = 0; k < GL; ++k) fc[k] = fn[k];
        }
        {
            const float a = O + __logf(v);
            const float x = a + trans[STOP_TAG * Kn + lane];
            float mx = x;
            #pragma unroll
            for (int off = 32; off; off >>= 1) mx = fmaxf(mx, __shfl_xor(mx, off));
            float se = __expf(x - mx);
            #pragma unroll
            for (int off = 32; off; off >>= 1) se += __shfl_xor(se, off);
            if (lane == 0)
                out[b] = (mx + __logf(se)) - (((gw[0] + gw[1]) + (gw[2] + gw[3])));
        }
        return;
    }

    // ================= Viterbi: A(value chain) | B/C(backpointers) | D(survivor chain) =================
    volatile int* pa = (volatile int*)prog_a;
    volatile int* pb = (volatile int*)prog_b;
    volatile int* pc = (volatile int*)prog_c;
    volatile int* pd = (volatile int*)prog_d;
    volatile int* db = (volatile int*)done_b;
    volatile int* dc = (volatile int*)done_c;
    if (wid == 0) { pa[lane] = 0; pb[lane] = 0; }
    if (wid == 1) { pc[lane] = 0; pd[lane] = 0; }
    if (wid == 2) { db[lane] = 0; dc[lane] = 0; }
    __syncthreads();   // the only barrier in the vit block

    float trS[Kn];     // lane j holds full row trans[j, 0..63]
    #pragma unroll
    for (int q = 0; q < Kn / 4; ++q) {
        const float4 t4 = ((const float4*)(trans + lane * Kn))[q];
        trS[4*q+0] = t4.x; trS[4*q+1] = t4.y; trS[4*q+2] = t4.z; trS[4*q+3] = t4.w;
    }

    if (wid == 0) {
        // ---- A: delta value chain (critical path) ----
        float v = (lane == START_TAG) ? 0.0f : NEGV;
        float fc[GL], fn[GL];
        #pragma unroll
        for (int k = 0; k < GL; ++k) fc[k] = feats[fb + (size_t)k * Kn + lane];
        for (int g = 0; g < NG; ++g) {
            if (g + 1 < NG) {
                const size_t base = fb + (size_t)(g + 1) * GL * Kn + lane;
                #pragma unroll
                for (int k = 0; k < GL; ++k) fn[k] = feats[base + (size_t)k * Kn];
            }
            const int tg0 = g * GL;
            if ((tg0 & 15) == 0 && tg0 >= RS) {  // ring backpressure (never hit: consumers faster)
                cfence();
                while (pb[lane] < tg0 - 16 || pc[lane] < tg0 - 16) {}
                cfence();
            }
            #pragma unroll
            for (int k = 0; k < GL; ++k) {
                const int t = tg0 + k;
                const int slot = t & (RS - 1);
                ring_v[slot][lane] = v;
                lgkm0();
                const float4* vp = (const float4*)ring_v[slot];
                float qm[16];
                #pragma unroll
                for (int q = 0; q < 16; ++q) {
                    const float4 dv = vp[q];
                    const float sx = dv.x + trS[4*q+0];
                    const float sy = dv.y + trS[4*q+1];
                    const float sz = dv.z + trS[4*q+2];
                    const float sw = dv.w + trS[4*q+3];
                    qm[q] = fmaxf(fmaxf(sx, sy), fmaxf(sz, sw));
                }
                float m8[8];
                #pragma unroll
                for (int q = 0; q < 8; ++q) m8[q] = fmaxf(qm[2*q], qm[2*q+1]);
                const float m4a = fmaxf(m8[0], m8[1]), m4b = fmaxf(m8[2], m8[3]);
                const float m4c = fmaxf(m8[4], m8[5]), m4d = fmaxf(m8[6], m8[7]);
                const float mm = fmaxf(fmaxf(m4a, m4b), fmaxf(m4c, m4d));
                ring_m[slot][lane] = mm;
                cfence();
                pa[lane] = t + 1;         // DS ops complete in order -> data visible first
                v = mm + fc[k];           // feat added after max, as in torch
            }
            #pragma unroll
            for (int k = 0; k < GL; ++k) fc[k] = fn[k];
        }
        // ---- terminal argmax (first index on ties) ----
        const float term = v + trans[STOP_TAG * Kn + lane];
        float bv = term;
        int bi = lane;
        #pragma unroll
        for (int off = 32; off; off >>= 1) {
            const float ov = __shfl_xor(bv, off);
            const int oi = __shfl_xor(bi, off);
            if (ov > bv || (ov == bv && oi < bi)) { bv = ov; bi = oi; }
        }
        if (lane == 0) out[BATCH + b] = bv;
        while (pd[lane] < Tn) __builtin_amdgcn_s_sleep(1);
        cfence();
        if (lane == 0) {
            int e = bi;
            for (int c = NCH - 1; c >= 0; --c) {
                echain[c] = (unsigned char)e;
                e = snap[c * Kn + e];
            }
        }
        lgkm0();
        while (db[lane] == 0 || dc[lane] == 0) __builtin_amdgcn_s_sleep(1);
        cfence();
        // ---- within-chunk reconstruction: lane = chunk ----
        int tag = echain[lane];
        float* po = out + 2 * BATCH + (size_t)b * Tn;
        const size_t bb = (size_t)b * Tn;
        for (int k = CH - 1; k >= 0; --k) {
            const int t = lane * CH + k;
            po[t] = (float)tag;
            tag = (int)bp8[(bb + (size_t)t) * Kn + tag];
        }
    } else if (wid == 1 || wid == 2) {
        // ---- B/C: argmax extraction off the critical path (B even t, C odd t) ----
        const int par = wid - 1;
        const size_t bb = (size_t)b * Tn;
        volatile int* my = (par == 0) ? pb : pc;
        for (int t = par; t < Tn; t += 2) {
            const int slot = t & (RS - 1);
            while (pa[lane] < t + 1) __builtin_amdgcn_s_sleep(1);
            cfence();
            if ((t & 31) == par && t >= RB) {   // ring_bp backpressure on D
                while (pd[lane] < t - 96) __builtin_amdgcn_s_sleep(1);
                cfence();
            }
            const float m = ring_m[slot][lane];
            const float4* vp = (const float4*)ring_v[slot];
            int qi[16];
            #pragma unroll
            for (int q = 0; q < 16; ++q) {
                const float4 dv = vp[q];
                const float sx = dv.x + trS[4*q+0];   // bitwise == A's adds
                const float sy = dv.y + trS[4*q+1];
                const float sz = dv.z + trS[4*q+2];
                const float sw = dv.w + trS[4*q+3];
                const int ix = (sx == m) ? 4*q+0 : 255;
                const int iy = (sy == m) ? 4*q+1 : 255;
                const int iz = (sz == m) ? 4*q+2 : 255;
                const int iw = (sw == m) ? 4*q+3 : 255;
                qi[q] = imin(imin(ix, iy), imin(iz, iw));
            }
            int i8[8];
            #pragma unroll
            for (int q = 0; q < 8; ++q) i8[q] = imin(qi[2*q], qi[2*q+1]);
            const int idx = imin(imin(imin(i8[0], i8[1]), imin(i8[2], i8[3])),
                                 imin(imin(i8[4], i8[5]), imin(i8[6], i8[7])));
            ring_bp[t & (RB - 1)][lane] = (unsigned char)idx;
            cfence();
            my[lane] = t + 1;
            bp8[(bb + (size_t)t) * Kn + lane] = (unsigned char)idx;
        }
        __asm__ volatile("s_waitcnt vmcnt(0)" ::: "memory");
        if (par == 0) db[lane] = 1; else dc[lane] = 1;
    } else {
        // ---- D: survivor shuffle chain + chunk snapshots ----
        int h = lane;
        for (int t = 0; t < Tn; ++t) {
            volatile int* pp = (t & 1) ? pc : pb;
            while (pp[lane] < t + 1) __builtin_amdgcn_s_sleep(1);
            cfence();
            const int bp = ring_bp[t & (RB - 1)][lane];
            h = __shfl(h, bp);
            if ((t & (CH - 1)) == (CH - 1)) {
                snap[(t >> 6) * Kn + lane] = (unsigned char)h;
                h = lane;
            }
            cfence();
            pd[lane] = t + 1;   // snap write precedes in program order -> in-order visible
        }
    }
}
} // namespace

extern "C" void kernel_launch(void* const* d_in, const int* in_sizes, int n_in,
                              void* d_out, int out_size, void* d_ws, size_t ws_size,
                              hipStream_t stream)
{
    const float* feats = (const float*)d_in[0];
    const int* tags   = (const int*)d_in[1];
    const float* trans = (const float*)d_in[2];
    float* out = (float*)d_out;
    unsigned char* bp = (unsigned char*)d_ws;  // needs 128*4096*64 B = 32 MB
    hipLaunchKernelGGL(crf_kernel, dim3(2 * BATCH), dim3(256), 0, stream,
                       feats, tags, trans, out, bp);
}

// Round 2
// 1811.958 us; speedup vs baseline: 1.1482x; 1.1482x over previous
//
#include <hip/hip_runtime.h>

namespace {
constexpr int Tn = 4096;
constexpr int Kn = 64;
constexpr int BATCH = 128;
constexpr int START_TAG = 62;
constexpr int STOP_TAG = 63;
constexpr float NEGV = -10000.0f;
constexpr int CH = 64;            // backtrace chunk length
constexpr int NCH = Tn / CH;      // 64 chunks
constexpr int GL = 8;             // feats burst length
constexpr int NG = Tn / GL;       // 512 groups
constexpr int RS = 128;           // delta ring slots (pow2)
constexpr int RB = 128;           // backpointer ring slots (pow2)
constexpr int CW = 16;            // consumer chunk width

__device__ __forceinline__ float rfl(float x) {
    return __uint_as_float(__builtin_amdgcn_readfirstlane(__float_as_uint(x)));
}
__device__ __forceinline__ void cfence() { __asm__ volatile("" ::: "memory"); }
__device__ __forceinline__ void lgkm0() { __asm__ volatile("s_waitcnt lgkmcnt(0)" ::: "memory"); }
__device__ __forceinline__ int imin(int a, int b) { return a < b ? a : b; }

__global__ __launch_bounds__(256, 1)
void crf_kernel(const float* __restrict__ feats,   // [B,T,K]
                const int* __restrict__ tags,      // [B,T]
                const float* __restrict__ trans,   // [K,K] trans[next,prev]
                float* __restrict__ out,           // [B] nll | [B] path_score | [B,T] path
                unsigned int* __restrict__ bp32)   // [B,T/4,K] packed backpointers
{
    const int tid = threadIdx.x;
    const int lane = tid & 63;
    const int wid = tid >> 6;
    const int b = blockIdx.x & (BATCH - 1);
    const size_t fb = (size_t)b * Tn * Kn;

    __shared__ float gw[4];
    __shared__ __align__(16) float vb[2][Kn];           // fwd ping-pong broadcast
    __shared__ __align__(16) float ring_v[RS][Kn];      // vit: delta_t vectors (32KB)
    __shared__ unsigned char ring_bp[RB][Kn];           // vit: backpointer ring
    __shared__ unsigned char snap[NCH * Kn];
    __shared__ unsigned char echain[NCH];
    __shared__ int prog_a[Kn], prog_b[Kn], prog_c[Kn], prog_d[Kn];
    __shared__ int done_b[Kn], done_c[Kn];

    if (blockIdx.x < BATCH) {
        // ================= forward log-partition + gold -> nll =================
        float gold = 0.0f;
        {
            const int t0 = tid * (Tn / 256);
            int prev = (tid == 0) ? START_TAG : tags[(size_t)b * Tn + t0 - 1];
            for (int k = 0; k < Tn / 256; ++k) {
                const int t = t0 + k;
                const int tg = tags[(size_t)b * Tn + t];
                gold += trans[tg * Kn + prev] + feats[fb + (size_t)t * Kn + tg];
                prev = tg;
            }
            if (tid == 255) gold += trans[STOP_TAG * Kn + prev];
            #pragma unroll
            for (int off = 32; off; off >>= 1) gold += __shfl_down(gold, off);
            if (lane == 0) gw[wid] = gold;
        }
        __syncthreads();
        if (wid != 0) return;   // single wave owns the recurrence

        float ES[Kn];           // lane j: exp(trans[j, 0..63])
        #pragma unroll
        for (int q = 0; q < Kn / 4; ++q) {
            const float4 t4 = ((const float4*)(trans + lane * Kn))[q];
            ES[4*q+0] = __expf(t4.x); ES[4*q+1] = __expf(t4.y);
            ES[4*q+2] = __expf(t4.z); ES[4*q+3] = __expf(t4.w);
        }
        float v = (lane == START_TAG) ? 1.0f : 0.0f;  // exp-domain one-hot
        float O = 0.0f;
        float fc[GL], fn[GL], Fc[GL];
        #pragma unroll
        for (int k = 0; k < GL; ++k) fc[k] = feats[fb + (size_t)k * Kn + lane];

        // software pipeline: reads for step t are issued at end of step t-1
        float4 rv0[16], rv1[16];
        vb[0][lane] = v;
        {
            const float4* p0 = (const float4*)vb[0];
            #pragma unroll
            for (int q = 0; q < 16; ++q) rv0[q] = p0[q];
        }

#define FWD_STEP(RV, RN, NB, K)  do {                                          \
        float wq_[4];                                                          \
        _Pragma("unroll")                                                      \
        for (int q = 0; q < 4; ++q) {                                          \
            const float4 v0 = (RV)[4*q+0], v1 = (RV)[4*q+1],                   \
                         v2 = (RV)[4*q+2], v3 = (RV)[4*q+3];                   \
            float s0 = 0.f, s1 = 0.f, s2 = 0.f, s3 = 0.f;                      \
            s0 = fmaf(ES[16*q+0],  v0.x, s0); s1 = fmaf(ES[16*q+1],  v0.y, s1);\
            s2 = fmaf(ES[16*q+2],  v0.z, s2); s3 = fmaf(ES[16*q+3],  v0.w, s3);\
            s0 = fmaf(ES[16*q+4],  v1.x, s0); s1 = fmaf(ES[16*q+5],  v1.y, s1);\
            s2 = fmaf(ES[16*q+6],  v1.z, s2); s3 = fmaf(ES[16*q+7],  v1.w, s3);\
            s0 = fmaf(ES[16*q+8],  v2.x, s0); s1 = fmaf(ES[16*q+9],  v2.y, s1);\
            s2 = fmaf(ES[16*q+10], v2.z, s2); s3 = fmaf(ES[16*q+11], v2.w, s3);\
            s0 = fmaf(ES[16*q+12], v3.x, s0); s1 = fmaf(ES[16*q+13], v3.y, s1);\
            s2 = fmaf(ES[16*q+14], v3.z, s2); s3 = fmaf(ES[16*q+15], v3.w, s3);\
            wq_[q] = (s0 + s1) + (s2 + s3);                                    \
        }                                                                      \
        const float w_ = ((wq_[0] + wq_[1]) + (wq_[2] + wq_[3])) * Fc[K];      \
        const float wz_ = rfl(w_);                                             \
        v = w_ * __builtin_amdgcn_rcpf(wz_);                                   \
        (NB)[lane] = v;                                                        \
        const float4* np_ = (const float4*)(NB);                               \
        _Pragma("unroll")                                                      \
        for (int q = 0; q < 16; ++q) (RN)[q] = np_[q];                         \
        O += __logf(wz_);                                                      \
    } while (0)

        for (int g = 0; g < NG; ++g) {
            if (g + 1 < NG) {
                const size_t base = fb + (size_t)(g + 1) * GL * Kn + lane;
                #pragma unroll
                for (int k = 0; k < GL; ++k) fn[k] = feats[base + (size_t)k * Kn];
            }
            #pragma unroll
            for (int k = 0; k < GL; ++k) Fc[k] = __expf(fc[k]);
            #pragma unroll
            for (int k = 0; k < GL; ++k) {
                if ((k & 1) == 0) FWD_STEP(rv0, rv1, vb[1], k);
                else              FWD_STEP(rv1, rv0, vb[0], k);
            }
            #pragma unroll
            for (int k = 0; k < GL; ++k) fc[k] = fn[k];
        }
#undef FWD_STEP
        {
            const float a = O + __logf(v);
            const float x = a + trans[STOP_TAG * Kn + lane];
            float mx = x;
            #pragma unroll
            for (int off = 32; off; off >>= 1) mx = fmaxf(mx, __shfl_xor(mx, off));
            float se = __expf(x - mx);
            #pragma unroll
            for (int off = 32; off; off >>= 1) se += __shfl_xor(se, off);
            if (lane == 0)
                out[b] = (mx + __logf(se)) - (((gw[0] + gw[1]) + (gw[2] + gw[3])));
        }
        return;
    }

    // ========= Viterbi: A(value chain) | B/C(argmax, 16-step chunks) | D(survivor) =========
    volatile int* pa = (volatile int*)prog_a;
    volatile int* pb = (volatile int*)prog_b;
    volatile int* pc = (volatile int*)prog_c;
    volatile int* pd = (volatile int*)prog_d;
    volatile int* db = (volatile int*)done_b;
    volatile int* dc = (volatile int*)done_c;
    if (wid == 0) { pa[lane] = 0; pb[lane] = 0; }
    if (wid == 1) { pc[lane] = 0; pd[lane] = 0; }
    if (wid == 2) { db[lane] = 0; dc[lane] = 0; }
    __syncthreads();   // the only barrier in the vit block

    float trS[Kn];     // lane j: trans[j, 0..63]
    #pragma unroll
    for (int q = 0; q < Kn / 4; ++q) {
        const float4 t4 = ((const float4*)(trans + lane * Kn))[q];
        trS[4*q+0] = t4.x; trS[4*q+1] = t4.y; trS[4*q+2] = t4.z; trS[4*q+3] = t4.w;
    }

    if (wid == 0) {
        // ---- A: delta value chain (critical path), software-pipelined ----
        float v = (lane == START_TAG) ? 0.0f : NEGV;
        float fc[GL], fn[GL];
        #pragma unroll
        for (int k = 0; k < GL; ++k) fc[k] = feats[fb + (size_t)k * Kn + lane];

        float4 rv0[16], rv1[16];
        ring_v[0][lane] = v;
        {
            const float4* p0 = (const float4*)ring_v[0];
            #pragma unroll
            for (int q = 0; q < 16; ++q) rv0[q] = p0[q];
        }

#define VIT_STEP(RV, RN, K)  do {                                              \
        const int t_ = g * GL + (K);                                           \
        float qm_[16];                                                         \
        _Pragma("unroll")                                                      \
        for (int q = 0; q < 16; ++q) {                                         \
            const float4 dv = (RV)[q];                                         \
            const float sx = dv.x + trS[4*q+0];                                \
            const float sy = dv.y + trS[4*q+1];                                \
            const float sz = dv.z + trS[4*q+2];                                \
            const float sw = dv.w + trS[4*q+3];                                \
            qm_[q] = fmaxf(fmaxf(sx, sy), fmaxf(sz, sw));                      \
        }                                                                      \
        float m8_[8];                                                          \
        _Pragma("unroll")                                                      \
        for (int q = 0; q < 8; ++q) m8_[q] = fmaxf(qm_[2*q], qm_[2*q+1]);      \
        const float mm = fmaxf(fmaxf(fmaxf(m8_[0], m8_[1]), fmaxf(m8_[2], m8_[3])), \
                               fmaxf(fmaxf(m8_[4], m8_[5]), fmaxf(m8_[6], m8_[7]))); \
        v = mm + fc[K];                 /* feat added after max, as in torch */ \
        float* nb_ = ring_v[(t_ + 1) & (RS - 1)];                              \
        nb_[lane] = v;                                                         \
        const float4* np_ = (const float4*)nb_;                                \
        _Pragma("unroll")                                                      \
        for (int q = 0; q < 16; ++q) (RN)[q] = np_[q];                         \
        cfence();                                                              \
        pa[lane] = t_ + 1;              /* in-order DS: ring write visible */  \
    } while (0)

        for (int g = 0; g < NG; ++g) {
            if (g + 1 < NG) {
                const size_t base = fb + (size_t)(g + 1) * GL * Kn + lane;
                #pragma unroll
                for (int k = 0; k < GL; ++k) fn[k] = feats[base + (size_t)k * Kn];
            }
            // ring backpressure: once per 32 steps, margin 88 (never hit in steady state)
            if ((g & 3) == 0 && g >= 16) {
                const int t0 = g * GL;
                cfence();
                while (pb[lane] < t0 - 88 || pc[lane] < t0 - 88)
                    __builtin_amdgcn_s_sleep(1);
                cfence();
            }
            #pragma unroll
            for (int k = 0; k < GL; ++k) {
                if ((k & 1) == 0) VIT_STEP(rv0, rv1, k);
                else              VIT_STEP(rv1, rv0, k);
            }
            #pragma unroll
            for (int k = 0; k < GL; ++k) fc[k] = fn[k];
        }
#undef VIT_STEP
        // ---- terminal argmax (first index on ties) ----
        const float term = v + trans[STOP_TAG * Kn + lane];
        float bv = term;
        int bi = lane;
        #pragma unroll
        for (int off = 32; off; off >>= 1) {
            const float ov = __shfl_xor(bv, off);
            const int oi = __shfl_xor(bi, off);
            if (ov > bv || (ov == bv && oi < bi)) { bv = ov; bi = oi; }
        }
        if (lane == 0) out[BATCH + b] = bv;
        while (pd[lane] < Tn) __builtin_amdgcn_s_sleep(1);
        cfence();
        if (lane == 0) {
            int e = bi;
            for (int c = NCH - 1; c >= 0; --c) {
                echain[c] = (unsigned char)e;
                e = snap[c * Kn + e];
            }
        }
        lgkm0();
        while (db[lane] == 0 || dc[lane] == 0) __builtin_amdgcn_s_sleep(1);
        cfence();
        // ---- within-chunk reconstruction: lane = chunk ----
        int tag = echain[lane];
        float* po = out + 2 * BATCH + (size_t)b * Tn;
        const size_t dwb = (size_t)b * (Tn / 4);
        for (int k = CH - 1; k >= 0; --k) {
            const int t = lane * CH + k;
            po[t] = (float)tag;
            tag = (int)((bp32[(dwb + (size_t)(t >> 2)) * Kn + tag] >> (8 * (t & 3))) & 63u);
        }
    } else if (wid == 1 || wid == 2) {
        // ---- B/C: argmax extraction, alternating 16-step chunks ----
        const int par = wid - 1;
        const size_t dwb = (size_t)b * (Tn / 4);
        volatile int* my = (par == 0) ? pb : pc;
        for (int c0 = par * CW; c0 < Tn; c0 += 2 * CW) {
            while (pa[lane] < c0 + CW) __builtin_amdgcn_s_sleep(1);
            cfence();
            if (c0 >= RB) {                       // ring_bp backpressure on D
                while (pd[lane] < c0 - (RB - CW)) __builtin_amdgcn_s_sleep(1);
                cfence();
            }
            for (int k4 = 0; k4 < CW; k4 += 4) {
                unsigned int bp4 = 0;
                #pragma unroll
                for (int k = 0; k < 4; ++k) {
                    const int t = c0 + k4 + k;
                    const float4* vp = (const float4*)ring_v[t & (RS - 1)];
                    float sa[64], qm[16];
                    #pragma unroll
                    for (int q = 0; q < 16; ++q) {
                        const float4 dv = vp[q];
                        sa[4*q+0] = dv.x + trS[4*q+0];   // bitwise == A's adds
                        sa[4*q+1] = dv.y + trS[4*q+1];
                        sa[4*q+2] = dv.z + trS[4*q+2];
                        sa[4*q+3] = dv.w + trS[4*q+3];
                        qm[q] = fmaxf(fmaxf(sa[4*q+0], sa[4*q+1]),
                                      fmaxf(sa[4*q+2], sa[4*q+3]));
                    }
                    float m8[8];
                    #pragma unroll
                    for (int q = 0; q < 8; ++q) m8[q] = fmaxf(qm[2*q], qm[2*q+1]);
                    const float m = fmaxf(fmaxf(fmaxf(m8[0], m8[1]), fmaxf(m8[2], m8[3])),
                                          fmaxf(fmaxf(m8[4], m8[5]), fmaxf(m8[6], m8[7])));
                    int qi[16];
                    #pragma unroll
                    for (int q = 0; q < 16; ++q) {
                        const int i0 = 4 * q;
                        const int ix = (sa[i0+0] == m) ? i0+0 : 255;
                        const int iy = (sa[i0+1] == m) ? i0+1 : 255;
                        const int iz = (sa[i0+2] == m) ? i0+2 : 255;
                        const int iw = (sa[i0+3] == m) ? i0+3 : 255;
                        qi[q] = imin(imin(ix, iy), imin(iz, iw));
                    }
                    int i8[8];
                    #pragma unroll
                    for (int q = 0; q < 8; ++q) i8[q] = imin(qi[2*q], qi[2*q+1]);
                    const int idx = imin(imin(imin(i8[0], i8[1]), imin(i8[2], i8[3])),
                                         imin(imin(i8[4], i8[5]), imin(i8[6], i8[7])));
                    ring_bp[t & (RB - 1)][lane] = (unsigned char)idx;
                    bp4 |= (unsigned int)idx << (8 * k);
                }
                bp32[(dwb + (size_t)((c0 + k4) >> 2)) * Kn + lane] = bp4;
            }
            cfence();
            my[lane] = c0 + CW;   // in-order DS: ring_bp writes visible first
        }
        __asm__ volatile("s_waitcnt vmcnt(0)" ::: "memory");
        if (par == 0) db[lane] = 1; else dc[lane] = 1;
    } else {
        // ---- D: survivor shuffle chain, 16-step chunks ----
        int h = lane;
        for (int c0 = 0; c0 < Tn; c0 += CW) {
            volatile int* pp = ((c0 >> 4) & 1) ? pc : pb;
            while (pp[lane] < c0 + CW) __builtin_amdgcn_s_sleep(1);
            cfence();
            int bpv[CW];
            #pragma unroll
            for (int k = 0; k < CW; ++k)
                bpv[k] = (int)ring_bp[(c0 + k) & (RB - 1)][lane];
            #pragma unroll
            for (int k = 0; k < CW; ++k) h = __shfl(h, bpv[k]);
            if (((c0 >> 4) & 3) == 3) {
                snap[(c0 >> 6) * Kn + lane] = (unsigned char)h;
                h = lane;
            }
            cfence();
            pd[lane] = c0 + CW;
        }
    }
}
} // namespace

extern "C" void kernel_launch(void* const* d_in, const int* in_sizes, int n_in,
                              void* d_out, int out_size, void* d_ws, size_t ws_size,
                              hipStream_t stream)
{
    const float* feats = (const float*)d_in[0];
    const int* tags   = (const int*)d_in[1];
    const float* trans = (const float*)d_in[2];
    float* out = (float*)d_out;
    unsigned int* bp = (unsigned int*)d_ws;  // needs 128*1024*64*4 B = 32 MB
    hipLaunchKernelGGL(crf_kernel, dim3(2 * BATCH), dim3(256), 0, stream,
                       feats, tags, trans, out, bp);
}

// Round 3
// 1683.547 us; speedup vs baseline: 1.2358x; 1.0763x over previous
//
#include <hip/hip_runtime.h>

namespace {
constexpr int Tn = 4096;
constexpr int Kn = 64;
constexpr int BATCH = 128;
constexpr int START_TAG = 62;
constexpr int STOP_TAG = 63;
constexpr float NEGV = -10000.0f;
constexpr int CH = 64;            // backtrace chunk length
constexpr int NCH = Tn / CH;      // 64 chunks
constexpr int GL = 8;             // feats burst length
constexpr int NG = Tn / GL;       // 512 groups
constexpr int RS = 128;           // delta/max ring slots (pow2)
constexpr int RB = 128;           // backpointer ring slots (pow2)
constexpr int CW = 16;            // consumer chunk width

__device__ __forceinline__ float rfl(float x) {
    return __uint_as_float(__builtin_amdgcn_readfirstlane(__float_as_uint(x)));
}
__device__ __forceinline__ void cfence() { __asm__ volatile("" ::: "memory"); }
__device__ __forceinline__ void lgkm0() { __asm__ volatile("s_waitcnt lgkmcnt(0)" ::: "memory"); }
__device__ __forceinline__ int imin(int a, int b) { return a < b ? a : b; }
__device__ __forceinline__ float m3(float a, float b, float c) {
    return fmaxf(fmaxf(a, b), c);   // clang fuses to v_max3_f32
}

__global__ __launch_bounds__(256, 1)
void crf_kernel(const float* __restrict__ feats,   // [B,T,K]
                const int* __restrict__ tags,      // [B,T]
                const float* __restrict__ trans,   // [K,K] trans[next,prev]
                float* __restrict__ out,           // [B] nll | [B] path_score | [B,T] path
                unsigned int* __restrict__ bp32)   // [B,T/4,K] packed backpointers
{
    const int tid = threadIdx.x;
    const int lane = tid & 63;
    const int wid = tid >> 6;
    const int b = blockIdx.x & (BATCH - 1);
    const size_t fb = (size_t)b * Tn * Kn;

    __shared__ float gw[4];
    __shared__ __align__(16) float vbuf[Kn];            // fwd broadcast buffer
    __shared__ __align__(16) float ring_v[RS][Kn];      // vit: delta_t vectors (32KB)
    __shared__ float ring_m[RS][Kn];                    // vit: pre-feat max m_t (32KB)
    __shared__ unsigned char ring_bp[RB][Kn];           // vit: backpointer ring
    __shared__ unsigned char snap[NCH * Kn];
    __shared__ unsigned char echain[NCH];
    __shared__ int prog_a[Kn], prog_b[Kn], prog_c[Kn], prog_d[Kn];
    __shared__ int done_b[Kn], done_c[Kn];

// gather full 64-float vector into 16 named float4 regs (single buffer)
#define GATHER16(BASE) do {                                                    \
        const float4* vp_ = (const float4*)(BASE);                             \
        g0 = vp_[0];  g1 = vp_[1];  g2 = vp_[2];  g3 = vp_[3];                 \
        g4 = vp_[4];  g5 = vp_[5];  g6 = vp_[6];  g7 = vp_[7];                 \
        g8 = vp_[8];  g9 = vp_[9];  g10 = vp_[10]; g11 = vp_[11];              \
        g12 = vp_[12]; g13 = vp_[13]; g14 = vp_[14]; g15 = vp_[15];            \
    } while (0)

    if (blockIdx.x < BATCH) {
        // ================= forward log-partition + gold -> nll =================
        float gold = 0.0f;
        {
            const int t0 = tid * (Tn / 256);
            int prev = (tid == 0) ? START_TAG : tags[(size_t)b * Tn + t0 - 1];
            for (int k = 0; k < Tn / 256; ++k) {
                const int t = t0 + k;
                const int tg = tags[(size_t)b * Tn + t];
                gold += trans[tg * Kn + prev] + feats[fb + (size_t)t * Kn + tg];
                prev = tg;
            }
            if (tid == 255) gold += trans[STOP_TAG * Kn + prev];
            #pragma unroll
            for (int off = 32; off; off >>= 1) gold += __shfl_down(gold, off);
            if (lane == 0) gw[wid] = gold;
        }
        __syncthreads();
        if (wid != 0) return;   // single wave owns the recurrence

        float ES[Kn];           // lane j: exp(trans[j, 0..63])
        #pragma unroll
        for (int q = 0; q < Kn / 4; ++q) {
            const float4 t4 = ((const float4*)(trans + lane * Kn))[q];
            ES[4*q+0] = __expf(t4.x); ES[4*q+1] = __expf(t4.y);
            ES[4*q+2] = __expf(t4.z); ES[4*q+3] = __expf(t4.w);
        }
        float v = (lane == START_TAG) ? 1.0f : 0.0f;  // exp-domain one-hot
        float O = 0.0f;
        float fc[GL], fn[GL], Fc[GL];
        #pragma unroll
        for (int k = 0; k < GL; ++k) fc[k] = feats[fb + (size_t)k * Kn + lane];

        float4 g0, g1, g2, g3, g4, g5, g6, g7, g8, g9, g10, g11, g12, g13, g14, g15;
        vbuf[lane] = v;
        GATHER16(vbuf);

#define FMAQ(Q, A, B2, C, D) ({                                                \
        float s0_ = 0.f, s1_ = 0.f, s2_ = 0.f, s3_ = 0.f;                      \
        s0_ = fmaf(ES[16*(Q)+0],  (A).x,  s0_); s1_ = fmaf(ES[16*(Q)+1],  (A).y,  s1_); \
        s2_ = fmaf(ES[16*(Q)+2],  (A).z,  s2_); s3_ = fmaf(ES[16*(Q)+3],  (A).w,  s3_); \
        s0_ = fmaf(ES[16*(Q)+4],  (B2).x, s0_); s1_ = fmaf(ES[16*(Q)+5],  (B2).y, s1_); \
        s2_ = fmaf(ES[16*(Q)+6],  (B2).z, s2_); s3_ = fmaf(ES[16*(Q)+7],  (B2).w, s3_); \
        s0_ = fmaf(ES[16*(Q)+8],  (C).x,  s0_); s1_ = fmaf(ES[16*(Q)+9],  (C).y,  s1_); \
        s2_ = fmaf(ES[16*(Q)+10], (C).z,  s2_); s3_ = fmaf(ES[16*(Q)+11], (C).w,  s3_); \
        s0_ = fmaf(ES[16*(Q)+12], (D).x,  s0_); s1_ = fmaf(ES[16*(Q)+13], (D).y,  s1_); \
        s2_ = fmaf(ES[16*(Q)+14], (D).z,  s2_); s3_ = fmaf(ES[16*(Q)+15], (D).w,  s3_); \
        (s0_ + s1_) + (s2_ + s3_); })

#define FWD_STEP(K) do {                                                       \
        const float w0_ = FMAQ(0, g0,  g1,  g2,  g3);                          \
        const float w1_ = FMAQ(1, g4,  g5,  g6,  g7);                          \
        const float w2_ = FMAQ(2, g8,  g9,  g10, g11);                         \
        const float w3_ = FMAQ(3, g12, g13, g14, g15);                         \
        const float w_ = ((w0_ + w1_) + (w2_ + w3_)) * Fc[K];                  \
        const float wz_ = rfl(w_);                                             \
        v = w_ * __builtin_amdgcn_rcpf(wz_);                                   \
        vbuf[lane] = v;                                                        \
        GATHER16(vbuf);               /* reads queue after write, in-order */  \
        O += __logf(wz_);             /* off-chain, in the read shadow */      \
    } while (0)

        for (int g = 0; g < NG; ++g) {
            if (g + 1 < NG) {
                const size_t base = fb + (size_t)(g + 1) * GL * Kn + lane;
                #pragma unroll
                for (int k = 0; k < GL; ++k) fn[k] = feats[base + (size_t)k * Kn];
            }
            #pragma unroll
            for (int k = 0; k < GL; ++k) Fc[k] = __expf(fc[k]);
            #pragma unroll
            for (int k = 0; k < GL; ++k) FWD_STEP(k);
            #pragma unroll
            for (int k = 0; k < GL; ++k) fc[k] = fn[k];
        }
#undef FWD_STEP
        {
            const float a = O + __logf(v);
            const float x = a + trans[STOP_TAG * Kn + lane];
            float mx = x;
            #pragma unroll
            for (int off = 32; off; off >>= 1) mx = fmaxf(mx, __shfl_xor(mx, off));
            float se = __expf(x - mx);
            #pragma unroll
            for (int off = 32; off; off >>= 1) se += __shfl_xor(se, off);
            if (lane == 0)
                out[b] = (mx + __logf(se)) - (((gw[0] + gw[1]) + (gw[2] + gw[3])));
        }
        return;
    }

    // ========= Viterbi: A(value chain) | B/C(argmax, 16-step chunks) | D(survivor) =========
    volatile int* pa = (volatile int*)prog_a;
    volatile int* pb = (volatile int*)prog_b;
    volatile int* pc = (volatile int*)prog_c;
    volatile int* pd = (volatile int*)prog_d;
    volatile int* db = (volatile int*)done_b;
    volatile int* dc = (volatile int*)done_c;
    if (wid == 0) { pa[lane] = 0; pb[lane] = 0; }
    if (wid == 1) { pc[lane] = 0; pd[lane] = 0; }
    if (wid == 2) { db[lane] = 0; dc[lane] = 0; }
    __syncthreads();   // the only barrier in the vit block

    float trS[Kn];     // lane j: trans[j, 0..63]
    #pragma unroll
    for (int q = 0; q < Kn / 4; ++q) {
        const float4 t4 = ((const float4*)(trans + lane * Kn))[q];
        trS[4*q+0] = t4.x; trS[4*q+1] = t4.y; trS[4*q+2] = t4.z; trS[4*q+3] = t4.w;
    }

    if (wid == 0) {
        // ---- A: delta value chain (critical path) ----
        float v = (lane == START_TAG) ? 0.0f : NEGV;
        float fc[GL], fn[GL];
        #pragma unroll
        for (int k = 0; k < GL; ++k) fc[k] = feats[fb + (size_t)k * Kn + lane];

        float4 g0, g1, g2, g3, g4, g5, g6, g7, g8, g9, g10, g11, g12, g13, g14, g15;
        ring_v[0][lane] = v;
        GATHER16(ring_v[0]);

#define VQ(Q, DV) ({                                                           \
        const float sx_ = (DV).x + trS[4*(Q)+0];                               \
        const float sy_ = (DV).y + trS[4*(Q)+1];                               \
        const float sz_ = (DV).z + trS[4*(Q)+2];                               \
        const float sw_ = (DV).w + trS[4*(Q)+3];                               \
        fmaxf(m3(sx_, sy_, sz_), sw_); })

#define VIT_STEP(K) do {                                                       \
        const int t_ = g * GL + (K);                                           \
        const float q0_  = VQ(0,  g0),  q1_  = VQ(1,  g1);                     \
        const float q2_  = VQ(2,  g2),  q3_  = VQ(3,  g3);                     \
        const float q4_  = VQ(4,  g4),  q5_  = VQ(5,  g5);                     \
        const float q6_  = VQ(6,  g6),  q7_  = VQ(7,  g7);                     \
        const float q8_  = VQ(8,  g8),  q9_  = VQ(9,  g9);                     \
        const float q10_ = VQ(10, g10), q11_ = VQ(11, g11);                    \
        const float q12_ = VQ(12, g12), q13_ = VQ(13, g13);                    \
        const float q14_ = VQ(14, g14), q15_ = VQ(15, g15);                    \
        const float r0_ = m3(q0_,  q1_,  q2_);                                 \
        const float r1_ = m3(q3_,  q4_,  q5_);                                 \
        const float r2_ = m3(q6_,  q7_,  q8_);                                 \
        const float r3_ = m3(q9_,  q10_, q11_);                                \
        const float r4_ = m3(q12_, q13_, q14_);                                \
        const float mm_ = fmaxf(m3(m3(r0_, r1_, r2_), r3_, r4_), q15_);        \
        v = mm_ + fc[K];                /* feat added after max, as in torch */ \
        float* nb_ = ring_v[(t_ + 1) & (RS - 1)];                              \
        nb_[lane] = v;                                                         \
        GATHER16(nb_);                  /* reads queue after write, in-order */ \
        ring_m[t_ & (RS - 1)][lane] = mm_;   /* in the read shadow */          \
    } while (0)

        for (int g = 0; g < NG; ++g) {
            if (g + 1 < NG) {
                const size_t base = fb + (size_t)(g + 1) * GL * Kn + lane;
                #pragma unroll
                for (int k = 0; k < GL; ++k) fn[k] = feats[base + (size_t)k * Kn];
            }
            // ring backpressure: once per 32 steps, margin 88 (never hit in steady state)
            if ((g & 3) == 0 && g >= 16) {
                const int t0 = g * GL;
                cfence();
                while (pb[lane] < t0 - 88 || pc[lane] < t0 - 88)
                    __builtin_amdgcn_s_sleep(1);
                cfence();
            }
            #pragma unroll
            for (int k = 0; k < GL; ++k) VIT_STEP(k);
            cfence();
            pa[lane] = g * GL + GL;     // one progress publish per 8 steps
            #pragma unroll
            for (int k = 0; k < GL; ++k) fc[k] = fn[k];
        }
#undef VIT_STEP
#undef VQ
        // ---- terminal argmax (first index on ties) ----
        const float term = v + trans[STOP_TAG * Kn + lane];
        float bv = term;
        int bi = lane;
        #pragma unroll
        for (int off = 32; off; off >>= 1) {
            const float ov = __shfl_xor(bv, off);
            const int oi = __shfl_xor(bi, off);
            if (ov > bv || (ov == bv && oi < bi)) { bv = ov; bi = oi; }
        }
        if (lane == 0) out[BATCH + b] = bv;
        while (pd[lane] < Tn) __builtin_amdgcn_s_sleep(1);
        cfence();
        if (lane == 0) {
            int e = bi;
            for (int c = NCH - 1; c >= 0; --c) {
                echain[c] = (unsigned char)e;
                e = snap[c * Kn + e];
            }
        }
        lgkm0();
        while (db[lane] == 0 || dc[lane] == 0) __builtin_amdgcn_s_sleep(1);
        cfence();
        // ---- within-chunk reconstruction: lane = chunk ----
        int tag = echain[lane];
        float* po = out + 2 * BATCH + (size_t)b * Tn;
        const size_t dwb = (size_t)b * (Tn / 4);
        for (int k = CH - 1; k >= 0; --k) {
            const int t = lane * CH + k;
            po[t] = (float)tag;
            tag = (int)((bp32[(dwb + (size_t)(t >> 2)) * Kn + tag] >> (8 * (t & 3))) & 63u);
        }
    } else if (wid == 1 || wid == 2) {
        // ---- B/C: argmax extraction, alternating 16-step chunks ----
        const int par = wid - 1;
        const size_t dwb = (size_t)b * (Tn / 4);
        volatile int* my = (par == 0) ? pb : pc;
        for (int c0 = par * CW; c0 < Tn; c0 += 2 * CW) {
            while (pa[lane] < c0 + CW) __builtin_amdgcn_s_sleep(1);
            cfence();
            if (c0 >= RB) {                       // ring_bp backpressure on D
                while (pd[lane] < c0 - (RB - CW)) __builtin_amdgcn_s_sleep(1);
                cfence();
            }
            for (int k4 = 0; k4 < CW; k4 += 4) {
                unsigned int bp4 = 0;
                #pragma unroll
                for (int k = 0; k < 4; ++k) {
                    const int t = c0 + k4 + k;
                    const float4* vp = (const float4*)ring_v[t & (RS - 1)];
                    const float m = ring_m[t & (RS - 1)][lane];   // A's exact max
                    int qi[16];
                    #pragma unroll
                    for (int q = 0; q < 16; ++q) {
                        const float4 dv = vp[q];
                        const float sx = dv.x + trS[4*q+0];   // bitwise == A's adds
                        const float sy = dv.y + trS[4*q+1];
                        const float sz = dv.z + trS[4*q+2];
                        const float sw = dv.w + trS[4*q+3];
                        const int ix = (sx == m) ? 4*q+0 : 255;
                        const int iy = (sy == m) ? 4*q+1 : 255;
                        const int iz = (sz == m) ? 4*q+2 : 255;
                        const int iw = (sw == m) ? 4*q+3 : 255;
                        qi[q] = imin(imin(ix, iy), imin(iz, iw));
                    }
                    int i8[8];
                    #pragma unroll
                    for (int q = 0; q < 8; ++q) i8[q] = imin(qi[2*q], qi[2*q+1]);
                    const int idx = imin(imin(imin(i8[0], i8[1]), imin(i8[2], i8[3])),
                                         imin(imin(i8[4], i8[5]), imin(i8[6], i8[7])));
                    ring_bp[t & (RB - 1)][lane] = (unsigned char)idx;
                    bp4 |= (unsigned int)idx << (8 * k);
                }
                bp32[(dwb + (size_t)((c0 + k4) >> 2)) * Kn + lane] = bp4;
            }
            cfence();
            my[lane] = c0 + CW;   // in-order DS: ring_bp writes visible first
        }
        __asm__ volatile("s_waitcnt vmcnt(0)" ::: "memory");
        if (par == 0) db[lane] = 1; else dc[lane] = 1;
    } else {
        // ---- D: survivor shuffle chain, 16-step chunks ----
        int h = lane;
        for (int c0 = 0; c0 < Tn; c0 += CW) {
            volatile int* pp = ((c0 >> 4) & 1) ? pc : pb;
            while (pp[lane] < c0 + CW) __builtin_amdgcn_s_sleep(1);
            cfence();
            int bpv[CW];
            #pragma unroll
            for (int k = 0; k < CW; ++k)
                bpv[k] = (int)ring_bp[(c0 + k) & (RB - 1)][lane];
            #pragma unroll
            for (int k = 0; k < CW; ++k) h = __shfl(h, bpv[k]);
            if (((c0 >> 4) & 3) == 3) {
                snap[(c0 >> 6) * Kn + lane] = (unsigned char)h;
                h = lane;
            }
            cfence();
            pd[lane] = c0 + CW;
        }
    }
#undef GATHER16
#undef FMAQ
}
} // namespace

extern "C" void kernel_launch(void* const* d_in, const int* in_sizes, int n_in,
                              void* d_out, int out_size, void* d_ws, size_t ws_size,
                              hipStream_t stream)
{
    const float* feats = (const float*)d_in[0];
    const int* tags   = (const int*)d_in[1];
    const float* trans = (const float*)d_in[2];
    float* out = (float*)d_out;
    unsigned int* bp = (unsigned int*)d_ws;  // needs 128*1024*64*4 B = 32 MB
    hipLaunchKernelGGL(crf_kernel, dim3(2 * BATCH), dim3(256), 0, stream,
                       feats, tags, trans, out, bp);
}